// Round 1
// baseline (278.888 us; speedup 1.0000x reference)
//
#include <hip/hip_runtime.h>

#define BATCH 8
#define SEQ   65536
#define CH    64
#define FILT  64
#define DLAT  256
#define TL    64          // output rows per block
#define PADW  72          // LDS row stride in bf16 (64 + 8 pad, keeps 16B align)

typedef __bf16 bfrag  __attribute__((ext_vector_type(8)));
typedef __bf16 bf16x4 __attribute__((ext_vector_type(4)));
typedef float  floatx4 __attribute__((ext_vector_type(4)));

// ---------------- prep: s[b,c], d[b,f], kT[k][f][c] (bf16) ----------------
__global__ __launch_bounds__(256) void prep_kernel(
    const float* __restrict__ ltnt, const float* __restrict__ ker,
    const float* __restrict__ Wd,   const float* __restrict__ bd,
    float* __restrict__ s_ws, float* __restrict__ d_ws, __bf16* __restrict__ kT)
{
    int blk = blockIdx.x;
    int tid = threadIdx.x;
    if (blk < BATCH) {
        int b = blk;
        __shared__ float red[4][64];
        __shared__ float s_sh[64];
        int f = tid & 63, p = tid >> 6;
        // partial dot over DLAT: part p covers j in [p*64, p*64+64)
        float sum = 0.f;
        for (int j = p * 64; j < p * 64 + 64; ++j)
            sum += ltnt[b * DLAT + j] * Wd[j * FILT + f];
        red[p][f] = sum;
        __syncthreads();
        if (tid < 64) {
            float tot = red[0][tid] + red[1][tid] + red[2][tid] + red[3][tid] + bd[tid];
            float sp = (tot > 20.f) ? tot : log1pf(expf(tot));
            float s = sp + 1.f;
            s_ws[b * 64 + tid] = s;
            s_sh[tid] = s;
        }
        __syncthreads();
        // d[b,f] = rsqrt( sum_{k,c} ker[k,c,f]^2 * s[c]^2 + eps ), part p covers 16 c's
        float s2 = 0.f;
        for (int k = 0; k < 3; ++k)
            for (int c = p * 16; c < p * 16 + 16; ++c) {
                float w = ker[k * 4096 + c * 64 + f];
                float sc = s_sh[c];
                s2 += w * w * sc * sc;
            }
        __syncthreads();   // step-3 reads of red complete before overwrite
        red[p][f] = s2;
        __syncthreads();
        if (tid < 64) {
            float tot = red[0][tid] + red[1][tid] + red[2][tid] + red[3][tid];
            d_ws[b * 64 + tid] = rsqrtf(tot + 1e-8f);
        }
    } else {
        // transpose+cast kernel: kT[k][f][c] = (bf16) ker[k][c][f]
        int cb = blk - BATCH;                     // 0..7, 1536 elems each
        for (int o = cb * 1536 + tid; o < (cb + 1) * 1536; o += 256) {
            int k = o >> 12, f = (o >> 6) & 63, c = o & 63;
            kT[o] = (__bf16)ker[k * 4096 + c * 64 + f];
        }
    }
}

// ---------------- main conv: one 64-row x 64-filter tile per block --------
__global__ __launch_bounds__(256, 4) void conv_kernel(
    const float* __restrict__ data, const float* __restrict__ s_ws,
    const float* __restrict__ d_ws, const __bf16* __restrict__ kT,
    float* __restrict__ out)
{
    __shared__ __bf16 xs[66 * PADW];        // modulated input rows t0-1 .. t0+64
    __shared__ __bf16 ks[3 * 64 * PADW];    // [k][f][c] padded

    int tid = threadIdx.x;
    int b   = blockIdx.x >> 10;             // 1024 tiles per batch
    int t0  = (blockIdx.x & 1023) * TL;

    // stage kernel (bf16, contiguous in ws) into padded LDS
    for (int i = tid; i < 1536; i += 256) { // 1536 chunks of 8 bf16 (16 B)
        int o8 = i * 8;
        int k = o8 >> 12, f = (o8 >> 6) & 63, c = o8 & 63;
        uint4 v = *reinterpret_cast<const uint4*>(kT + o8);
        *reinterpret_cast<uint4*>(&ks[(k * 64 + f) * PADW + c]) = v;
    }

    // stage x * s  -> bf16 LDS
    const float* xb = data + (size_t)b * SEQ * CH;
    const float* sb = s_ws + b * 64;
    for (int i = tid; i < 66 * 16; i += 256) {
        int row = i >> 4;
        int c4  = (i & 15) * 4;
        int g   = t0 - 1 + row;
        float4 v = make_float4(0.f, 0.f, 0.f, 0.f);
        if (g >= 0 && g < SEQ)
            v = *reinterpret_cast<const float4*>(xb + (size_t)g * CH + c4);
        float4 sv = *reinterpret_cast<const float4*>(sb + c4);
        bf16x4 pv;
        pv[0] = (__bf16)(v.x * sv.x);
        pv[1] = (__bf16)(v.y * sv.y);
        pv[2] = (__bf16)(v.z * sv.z);
        pv[3] = (__bf16)(v.w * sv.w);
        *reinterpret_cast<bf16x4*>(&xs[row * PADW + c4]) = pv;
    }
    __syncthreads();

    int wave  = tid >> 6;
    int lane  = tid & 63;
    int m     = lane & 15;
    int q     = lane >> 4;
    int rbase = wave * 16;   // this wave's 16 output rows

    floatx4 acc[4] = {floatx4{0,0,0,0}, floatx4{0,0,0,0},
                      floatx4{0,0,0,0}, floatx4{0,0,0,0}};

    // A fragments: xs row (rbase + k + m)  [xs[0] == global row t0-1]
    bfrag afr[3][2];
    #pragma unroll
    for (int k = 0; k < 3; ++k)
        #pragma unroll
        for (int chh = 0; chh < 2; ++chh)
            afr[k][chh] = *reinterpret_cast<const bfrag*>(
                &xs[(rbase + k + m) * PADW + chh * 32 + q * 8]);

    #pragma unroll
    for (int nt = 0; nt < 4; ++nt) {
        #pragma unroll
        for (int k = 0; k < 3; ++k) {
            #pragma unroll
            for (int chh = 0; chh < 2; ++chh) {
                bfrag bfr = *reinterpret_cast<const bfrag*>(
                    &ks[(k * 64 + nt * 16 + m) * PADW + chh * 32 + q * 8]);
                acc[nt] = __builtin_amdgcn_mfma_f32_16x16x32_bf16(
                    afr[k][chh], bfr, acc[nt], 0, 0, 0);
            }
        }
    }

    // epilogue: out[b, t0+row, f] = acc * d[b,f]
    float* ob = out + ((size_t)b * SEQ + t0) * FILT;
    const float* db = d_ws + b * 64;
    #pragma unroll
    for (int nt = 0; nt < 4; ++nt) {
        float dm = db[nt * 16 + m];
        #pragma unroll
        for (int r = 0; r < 4; ++r) {
            int row = rbase + q * 4 + r;
            ob[(size_t)row * FILT + nt * 16 + m] = acc[nt][r] * dm;
        }
    }
}

// ---------------------------------------------------------------------------
extern "C" void kernel_launch(void* const* d_in, const int* in_sizes, int n_in,
                              void* d_out, int out_size, void* d_ws, size_t ws_size,
                              hipStream_t stream) {
    const float* data = (const float*)d_in[0];
    const float* ltnt = (const float*)d_in[1];
    const float* ker  = (const float*)d_in[2];
    const float* Wd   = (const float*)d_in[3];
    const float* bd   = (const float*)d_in[4];
    float* out = (float*)d_out;

    float*  s_ws = (float*)d_ws;                       // 512 f32
    float*  d_wsp = s_ws + 512;                        // 512 f32
    __bf16* kT   = (__bf16*)((char*)d_ws + 4096);      // 12288 bf16

    prep_kernel<<<16, 256, 0, stream>>>(ltnt, ker, Wd, bd, s_ws, d_wsp, kT);
    conv_kernel<<<BATCH * (SEQ / TL), 256, 0, stream>>>(data, s_ws, d_wsp, kT, out);
}

// Round 2
// 275.868 us; speedup vs baseline: 1.0109x; 1.0109x over previous
//
#include <hip/hip_runtime.h>

#define BATCH 8
#define SEQ   65536
#define CH    64
#define FILT  64
#define DLAT  256

typedef __bf16 bfrag  __attribute__((ext_vector_type(8)));
typedef float  floatx4 __attribute__((ext_vector_type(4)));

// ------------- prep: s, d, and folded kernel kmod[b][k][f][c] (bf16) -------
// kmod[b][k][f][c] = ker[k][c][f] * s[b][c] * d[b][f]
__global__ __launch_bounds__(256) void prep_kernel(
    const float* __restrict__ ltnt, const float* __restrict__ ker,
    const float* __restrict__ Wd,   const float* __restrict__ bd,
    __bf16* __restrict__ kmod)
{
    int b = blockIdx.x, tid = threadIdx.x;
    __shared__ float red[4][64];
    __shared__ float s_sh[64];
    __shared__ float d_sh[64];
    int f = tid & 63, p = tid >> 6;

    // s = softplus(ltnt @ Wd + bd) + 1
    float sum = 0.f;
    #pragma unroll 8
    for (int j = p * 64; j < p * 64 + 64; ++j)
        sum += ltnt[b * DLAT + j] * Wd[j * FILT + f];
    red[p][f] = sum;
    __syncthreads();
    if (tid < 64) {
        float tot = red[0][tid] + red[1][tid] + red[2][tid] + red[3][tid] + bd[tid];
        float sp = (tot > 20.f) ? tot : log1pf(expf(tot));
        s_sh[tid] = sp + 1.f;
    }
    __syncthreads();

    // d[f] = rsqrt( sum_{k,c} (ker[k,c,f]*s[c])^2 + eps )   (f32, matches ref)
    float s2 = 0.f;
    for (int k = 0; k < 3; ++k)
        #pragma unroll
        for (int c = p * 16; c < p * 16 + 16; ++c) {
            float w = ker[k * 4096 + c * 64 + f];
            float sc = s_sh[c];
            s2 += w * w * sc * sc;
        }
    __syncthreads();
    red[p][f] = s2;
    __syncthreads();
    if (tid < 64) {
        float tot = red[0][tid] + red[1][tid] + red[2][tid] + red[3][tid];
        d_sh[tid] = rsqrtf(tot + 1e-8f);
    }
    __syncthreads();

    // folded kernel, bf16, layout [k][f][c] contiguous in c
    for (int o = tid; o < 3 * 64 * 64; o += 256) {
        int k = o >> 12, ff = (o >> 6) & 63, c = o & 63;
        kmod[b * 12288 + o] = (__bf16)(ker[k * 4096 + c * 64 + ff] * s_sh[c] * d_sh[ff]);
    }
}

// ---------------------------- conv (no LDS) --------------------------------
struct RawA { float4 v[3][2][2]; };   // [tap k][chh][lo/hi float4]

__device__ __forceinline__ float4 scale4(float4 v, float s) {
    v.x *= s; v.y *= s; v.z *= s; v.w *= s; return v;
}

__device__ __forceinline__ RawA loadA(const float* __restrict__ xb,
                                      int r0, int m, int q) {
    RawA r;
    if (r0 >= 1 && r0 <= SEQ - 17) {            // interior fast path (uniform)
        const float* p = xb + (size_t)(r0 + m - 1) * CH + q * 8;
        #pragma unroll
        for (int k = 0; k < 3; ++k)
            #pragma unroll
            for (int h = 0; h < 2; ++h) {
                r.v[k][h][0] = *(const float4*)(p + k * CH + h * 32);
                r.v[k][h][1] = *(const float4*)(p + k * CH + h * 32 + 4);
            }
    } else {                                    // batch-edge tiles only
        #pragma unroll
        for (int k = 0; k < 3; ++k) {
            int g = r0 + m - 1 + k;
            bool ok = (unsigned)g < (unsigned)SEQ;
            const float* p = xb + (size_t)(ok ? g : 0) * CH + q * 8;
            float sc = ok ? 1.f : 0.f;
            #pragma unroll
            for (int h = 0; h < 2; ++h) {
                r.v[k][h][0] = scale4(*(const float4*)(p + h * 32), sc);
                r.v[k][h][1] = scale4(*(const float4*)(p + h * 32 + 4), sc);
            }
        }
    }
    return r;
}

__device__ __forceinline__ bfrag cvt8(float4 a, float4 b) {
    bfrag r;
    r[0] = (__bf16)a.x; r[1] = (__bf16)a.y; r[2] = (__bf16)a.z; r[3] = (__bf16)a.w;
    r[4] = (__bf16)b.x; r[5] = (__bf16)b.y; r[6] = (__bf16)b.z; r[7] = (__bf16)b.w;
    return r;
}

__global__ __launch_bounds__(256, 2) void conv_kernel(
    const float* __restrict__ data, const __bf16* __restrict__ kmod,
    float* __restrict__ out)
{
    int tid  = threadIdx.x;
    int b    = blockIdx.x >> 6;        // 64 blocks per batch
    int blk  = blockIdx.x & 63;        // 1024 rows per block
    int wave = tid >> 6, lane = tid & 63;
    int m = lane & 15, q = lane >> 4;

    // B fragments (folded kernel) -> registers, once. 24 frags = 96 VGPRs.
    const __bf16* kb = kmod + b * 12288;
    bfrag Bf[4][3][2];
    #pragma unroll
    for (int nt = 0; nt < 4; ++nt)
        #pragma unroll
        for (int k = 0; k < 3; ++k)
            #pragma unroll
            for (int h = 0; h < 2; ++h)
                Bf[nt][k][h] = *(const bfrag*)(kb + (k * 64 + nt * 16 + m) * 64 + h * 32 + q * 8);

    const float* xb = data + (size_t)b * SEQ * CH;
    float*       ob = out  + (size_t)b * SEQ * FILT;

    // wave-interleaved 16-row tiles: r0 = blk*1024 + wave*16 + t*64
    int base = blk * 1024 + wave * 16;

    RawA raw = loadA(xb, base, m, q);
    bfrag Af[3][2];
    #pragma unroll
    for (int k = 0; k < 3; ++k)
        #pragma unroll
        for (int h = 0; h < 2; ++h)
            Af[k][h] = cvt8(raw.v[k][h][0], raw.v[k][h][1]);

    #pragma unroll 1
    for (int t = 0; t < 16; ++t) {
        int r0 = base + t * 64;

        if (t < 15)                     // issue next tile's loads (prefetch)
            raw = loadA(xb, r0 + 64, m, q);

        floatx4 acc[4] = {floatx4{0,0,0,0}, floatx4{0,0,0,0},
                          floatx4{0,0,0,0}, floatx4{0,0,0,0}};
        #pragma unroll
        for (int nt = 0; nt < 4; ++nt)
            #pragma unroll
            for (int k = 0; k < 3; ++k)
                #pragma unroll
                for (int h = 0; h < 2; ++h)
                    acc[nt] = __builtin_amdgcn_mfma_f32_16x16x32_bf16(
                        Af[k][h], Bf[nt][k][h], acc[nt], 0, 0, 0);

        // store 16 rows x 64 filters (streaming, never re-read)
        float* op = ob + (size_t)r0 * FILT;
        #pragma unroll
        for (int nt = 0; nt < 4; ++nt)
            #pragma unroll
            for (int r = 0; r < 4; ++r)
                __builtin_nontemporal_store(acc[nt][r],
                    op + (size_t)(q * 4 + r) * FILT + nt * 16 + m);

        if (t < 15) {                   // convert prefetched tile (waits here,
            #pragma unroll              //  after MFMAs, not before)
            for (int k = 0; k < 3; ++k)
                #pragma unroll
                for (int h = 0; h < 2; ++h)
                    Af[k][h] = cvt8(raw.v[k][h][0], raw.v[k][h][1]);
        }
    }
}

// ---------------------------------------------------------------------------
extern "C" void kernel_launch(void* const* d_in, const int* in_sizes, int n_in,
                              void* d_out, int out_size, void* d_ws, size_t ws_size,
                              hipStream_t stream) {
    const float* data = (const float*)d_in[0];
    const float* ltnt = (const float*)d_in[1];
    const float* ker  = (const float*)d_in[2];
    const float* Wd   = (const float*)d_in[3];
    const float* bd   = (const float*)d_in[4];
    float* out = (float*)d_out;

    __bf16* kmod = (__bf16*)d_ws;     // 8 * 12288 bf16 = 192 KiB

    prep_kernel<<<BATCH, 256, 0, stream>>>(ltnt, ker, Wd, bd, kmod);
    conv_kernel<<<BATCH * 64, 256, 0, stream>>>(data, kmod, out);
}